// Round 1
// baseline (361.483 us; speedup 1.0000x reference)
//
#include <hip/hip_runtime.h>
#include <math.h>

#define B_ 16
#define S_ 512
#define D_ 768
#define H_ 12
#define DH_ 64
#define BH_ (B_*H_)     // 192
#define MTOT (B_*S_)    // 8192
#define NTOT (3*D_)     // 2304

typedef unsigned short ushort_t;
typedef __attribute__((ext_vector_type(8))) short bf16x8;
typedef __attribute__((ext_vector_type(4))) float f32x4;

__device__ __forceinline__ unsigned short f2bf(float x){
    unsigned u = __float_as_uint(x);
    unsigned r = (u + 0x7FFFu + ((u >> 16) & 1u)) >> 16;
    return (unsigned short)r;
}
__device__ __forceinline__ float bf2f(unsigned short b){
    return __uint_as_float(((unsigned)b) << 16);
}

__device__ __forceinline__ void cp16(const void* g, void* l){
    __builtin_amdgcn_global_load_lds(
        (const __attribute__((address_space(1))) unsigned int*)g,
        (__attribute__((address_space(3))) unsigned int*)l, 16, 0, 0);
}

// ---------------------------------------------------------------------------
// f32 -> single bf16 (round-to-nearest), 4 elems/thread
// ---------------------------------------------------------------------------
__global__ __launch_bounds__(256)
void convert_x(const float* __restrict__ src, ushort_t* __restrict__ dst, int n4)
{
    int i = blockIdx.x * 256 + threadIdx.x;
    if (i >= n4) return;
    float4 x = ((const float4*)src)[i];
    union { ushort_t u[4]; uint2 v; } p;
    p.u[0] = f2bf(x.x); p.u[1] = f2bf(x.y);
    p.u[2] = f2bf(x.z); p.u[3] = f2bf(x.w);
    ((uint2*)dst)[i] = p.v;
}

// weights: split hi/lo, all three matrices in one launch
__global__ __launch_bounds__(256)
void convert_w(const float* __restrict__ Wq, const float* __restrict__ Wk,
               const float* __restrict__ Wv, ushort_t* __restrict__ hi,
               ushort_t* __restrict__ lo)
{
    const float* src = (blockIdx.z==0) ? Wq : (blockIdx.z==1) ? Wk : Wv;
    const int n4 = D_*D_/4;
    int i = blockIdx.x * 256 + threadIdx.x;
    if (i >= n4) return;
    size_t off4 = (size_t)blockIdx.z * n4;
    float4 x = ((const float4*)src)[i];
    union { ushort_t u[4]; uint2 v; } ph, pl;
    float xs[4] = {x.x, x.y, x.z, x.w};
    #pragma unroll
    for (int c = 0; c < 4; c++){
        unsigned short h = f2bf(xs[c]);
        ph.u[c] = h;
        pl.u[c] = f2bf(xs[c] - bf2f(h));
    }
    ((uint2*)hi)[off4 + i] = ph.v;
    ((uint2*)lo)[off4 + i] = pl.v;
}

// ---------------------------------------------------------------------------
// MFMA GEMM: C[m,n] = sum_k Xbf[m,k] * W[n,k] + bias; X single bf16, W hi/lo
// (2 MFMAs per tile-pair). mat 0 -> Q hi/lo, 1 -> K hi/lo,
// 2 -> V TRANSPOSED hi/lo (V^T[bh][d][s], bf16 split) for MFMA PV.
// ---------------------------------------------------------------------------
#define BM 128
#define BN 128
#define BK 32

__global__ __launch_bounds__(256)
void gemm_split(const ushort_t* __restrict__ A,
                const ushort_t* __restrict__ Bhi, const ushort_t* __restrict__ Blo,
                const float* __restrict__ bq, const float* __restrict__ bk,
                const float* __restrict__ bv,
                ushort_t* __restrict__ qhi, ushort_t* __restrict__ qlo,
                ushort_t* __restrict__ khi, ushort_t* __restrict__ klo,
                ushort_t* __restrict__ vthi, ushort_t* __restrict__ vtlo)
{
    __shared__ ushort_t Ah[BM*BK], Bh[BN*BK], Bl[BN*BK];  // 24 KB

    const int tid  = threadIdx.x;
    const int lane = tid & 63, wave = tid >> 6;
    const int m0 = blockIdx.y * BM, n0 = blockIdx.x * BN;
    const int wm = (wave >> 1) * 64, wn = (wave & 1) * 64;

    f32x4 acc[4][4];
    #pragma unroll
    for (int i=0;i<4;i++)
        #pragma unroll
        for (int j=0;j<4;j++) acc[i][j] = (f32x4){0.f,0.f,0.f,0.f};

    const int r0 = tid >> 2, c0 = (tid & 3) * 8;
    const size_t ga0 = (size_t)(m0 + r0)      * D_ + c0;
    const size_t ga1 = (size_t)(m0 + 64 + r0) * D_ + c0;
    const size_t gb0 = (size_t)(n0 + r0)      * D_ + c0;
    const size_t gb1 = (size_t)(n0 + 64 + r0) * D_ + c0;
    const int l0 = wave * 512;
    const int l1 = 2048 + wave * 512;

    const int fr = lane & 15, kc = (lane >> 4) * 8;

    for (int k0 = 0; k0 < D_; k0 += BK) {
        cp16(A   + ga0 + k0, Ah + l0);
        cp16(A   + ga1 + k0, Ah + l1);
        cp16(Bhi + gb0 + k0, Bh + l0);
        cp16(Bhi + gb1 + k0, Bh + l1);
        cp16(Blo + gb0 + k0, Bl + l0);
        cp16(Blo + gb1 + k0, Bl + l1);
        __syncthreads();

        bf16x8 fa[4], fbh[4], fbl[4];
        #pragma unroll
        for (int i = 0; i < 4; i++){
            fa[i]  = *(const bf16x8*)&Ah[(wm + i*16 + fr)*BK + kc];
            fbh[i] = *(const bf16x8*)&Bh[(wn + i*16 + fr)*BK + kc];
            fbl[i] = *(const bf16x8*)&Bl[(wn + i*16 + fr)*BK + kc];
        }
        #pragma unroll
        for (int i = 0; i < 4; i++)
            #pragma unroll
            for (int j = 0; j < 4; j++){
                acc[i][j] = __builtin_amdgcn_mfma_f32_16x16x32_bf16(fa[i], fbh[j], acc[i][j], 0,0,0);
                acc[i][j] = __builtin_amdgcn_mfma_f32_16x16x32_bf16(fa[i], fbl[j], acc[i][j], 0,0,0);
            }
        __syncthreads();
    }

    const int mat = n0 / D_;   // block-uniform
    const float* bias = (mat==0) ? bq : (mat==1) ? bk : bv;
    const int col = lane & 15, rbase = (lane >> 4) * 4;
    #pragma unroll
    for (int j = 0; j < 4; j++){
        int nn = n0 + wn + j*16 + col - mat*D_;
        int h = nn >> 6, d = nn & 63;
        float bsv = bias[nn];
        if (mat == 2){
            // V^T hi/lo: thread owns 4 consecutive s (r=0..3) at fixed d
            #pragma unroll
            for (int i = 0; i < 4; i++){
                int m = m0 + wm + i*16 + rbase;          // s0; bb/s const over r
                int bb = m >> 9, s = m & 511;
                size_t idx = (((size_t)bb*H_ + h)*DH_ + d)*S_ + s;
                ushort4 vh4, vl4;
                ushort_t* hp = (ushort_t*)&vh4;
                ushort_t* lp = (ushort_t*)&vl4;
                #pragma unroll
                for (int r = 0; r < 4; r++){
                    float val = acc[i][j][r] + bsv;
                    ushort_t hv = f2bf(val);
                    hp[r] = hv;
                    lp[r] = f2bf(val - bf2f(hv));
                }
                *(ushort4*)&vthi[idx] = vh4;
                *(ushort4*)&vtlo[idx] = vl4;
            }
        } else {
            #pragma unroll
            for (int i = 0; i < 4; i++){
                #pragma unroll
                for (int r = 0; r < 4; r++){
                    int m = m0 + wm + i*16 + rbase + r;
                    int bb = m >> 9, s = m & 511;
                    size_t idx = (((size_t)bb*H_ + h)*S_ + s)*DH_ + d;
                    float val = acc[i][j][r] + bsv;
                    ushort_t hv = f2bf(val);
                    ushort_t lv = f2bf(val - bf2f(hv));
                    if (mat == 0){ qhi[idx] = hv; qlo[idx] = lv; }
                    else         { khi[idx] = hv; klo[idx] = lv; }
                }
            }
        }
    }
}

// ---------------------------------------------------------------------------
// MFMA sparsemax attention.
// Phase 1: QK^T scores via hi/lo MFMA -> LDS owner layout (unchanged).
// Phase 2: quad-owns-row Michelot (tree-reduced partial sums).
// Phase 3 (NEW): PV as dense MFMA. p -> bf16 hi/lo packed into the reused
// sc LDS buffer (XOR-swizzled rows, T2 pattern), V^T hi/lo B-fragments from
// global (L2-resident per head), 3 MFMAs per 32-key chunk, 2x3 accumulators.
// Block swizzle: all 32 blocks of a head land on one XCD (K/V L2 locality).
// ---------------------------------------------------------------------------
__global__ __launch_bounds__(256)
void attn_mfma(const ushort_t* __restrict__ Qhi, const ushort_t* __restrict__ Qlo,
               const ushort_t* __restrict__ Khi, const ushort_t* __restrict__ Klo,
               const ushort_t* __restrict__ Vthi, const ushort_t* __restrict__ Vtlo,
               const float* __restrict__ mask, float* __restrict__ out)
{
    __shared__ float sc[16*16*36];   // 36 KB: [row][owner][36]; reused for P

    const int lane = threadIdx.x & 63;
    const int wave = threadIdx.x >> 6;         // 0..3
    const int fr = lane & 15, quad = lane >> 4;

    // XCD-bijective swizzle: 6144 blocks, 768 per XCD => 24 whole heads/XCD
    const int orig = blockIdx.x;
    const int swz  = (orig & 7) * (BH_*32/8) + (orig >> 3);
    const int bh = swz >> 5;
    const int q0 = (swz & 31) * 16;
    const int b = bh / H_, h = bh % H_;
    const size_t hb = (size_t)bh * S_ * DH_;
    const int kw0 = wave * 128;                // phase-1 key range

    // ---- Phase 1: QK^T scores (Q hi/lo x K hi/lo, 6 MFMAs per tile) -------
    bf16x8 qh[2], ql[2];
    {
        const ushort_t* qp  = Qhi + hb + (size_t)(q0 + fr)*DH_ + quad*8;
        const ushort_t* qp2 = Qlo + hb + (size_t)(q0 + fr)*DH_ + quad*8;
        qh[0] = *(const bf16x8*)qp;   qh[1] = *(const bf16x8*)(qp + 32);
        ql[0] = *(const bf16x8*)qp2;  ql[1] = *(const bf16x8*)(qp2 + 32);
    }

    f32x4 acc[8];
    #pragma unroll
    for (int j=0;j<8;j++) acc[j] = (f32x4){0.f,0.f,0.f,0.f};

    #pragma unroll
    for (int j=0;j<8;j++){
        const ushort_t* kp  = Khi + hb + (size_t)(kw0 + j*16 + fr)*DH_ + quad*8;
        const ushort_t* kp2 = Klo + hb + (size_t)(kw0 + j*16 + fr)*DH_ + quad*8;
        bf16x8 kh0 = *(const bf16x8*)kp;
        bf16x8 kh1 = *(const bf16x8*)(kp + 32);
        bf16x8 kl0 = *(const bf16x8*)kp2;
        bf16x8 kl1 = *(const bf16x8*)(kp2 + 32);
        acc[j] = __builtin_amdgcn_mfma_f32_16x16x32_bf16(qh[0], kh0, acc[j], 0,0,0);
        acc[j] = __builtin_amdgcn_mfma_f32_16x16x32_bf16(qh[1], kh1, acc[j], 0,0,0);
        acc[j] = __builtin_amdgcn_mfma_f32_16x16x32_bf16(ql[0], kh0, acc[j], 0,0,0);
        acc[j] = __builtin_amdgcn_mfma_f32_16x16x32_bf16(ql[1], kh1, acc[j], 0,0,0);
        acc[j] = __builtin_amdgcn_mfma_f32_16x16x32_bf16(qh[0], kl0, acc[j], 0,0,0);
        acc[j] = __builtin_amdgcn_mfma_f32_16x16x32_bf16(qh[1], kl1, acc[j], 0,0,0);
    }

    // scale + mask, scatter to owner layout: key k -> slot k>>5, pos k&31
    const float* mrow = mask + b * S_;
    #pragma unroll
    for (int j=0;j<8;j++){
        int k = kw0 + j*16 + fr;
        float mv = mrow[k];
        int base = (k >> 5)*36 + (k & 31);
        #pragma unroll
        for (int r=0;r<4;r++){
            int row = quad*4 + r;
            sc[row*576 + base] = acc[j][r]*0.125f + mv;
        }
    }
    __syncthreads();

    // ---- Phase 2: quad q of wave w owns row w*4+q; lane fr holds keys
    //      [fr*32, fr*32+32) of that row.
    const int row = wave*4 + quad;
    float z[32];
    {
        const float* zp = &sc[row*576 + fr*36];
        #pragma unroll
        for (int jj=0;jj<8;jj++){
            float4 t = *(const float4*)(zp + jj*4);
            z[jj*4+0]=t.x; z[jj*4+1]=t.y; z[jj*4+2]=t.z; z[jj*4+3]=t.w;
        }
    }
    __syncthreads();   // all sc reads done; sc may now be overwritten by P

    // row max: depth-5 tree + 4-step intra-quad butterfly
    float tau;
    {
        float red[16];
        #pragma unroll
        for (int i=0;i<16;i++) red[i] = fmaxf(z[i], z[i+16]);
        #pragma unroll
        for (int i=0;i<8;i++)  red[i] = fmaxf(red[i], red[i+8]);
        #pragma unroll
        for (int i=0;i<4;i++)  red[i] = fmaxf(red[i], red[i+4]);
        float mm = fmaxf(fmaxf(red[0],red[1]), fmaxf(red[2],red[3]));
        #pragma unroll
        for (int off=1; off<16; off<<=1) mm = fmaxf(mm, __shfl_xor(mm, off, 64));
        tau = mm - 1.0f;
    }

    // Michelot fixed-point: 4-way partial sums (depth-8 chains), butterfly
    for (int it=0; it<16; it++){
        float s0=0.f,s1=0.f,s2=0.f,s3=0.f;
        float k0=0.f,k1=0.f,k2=0.f,k3=0.f;
        #pragma unroll
        for (int i=0;i<32;i+=4){
            float z0=z[i], z1=z[i+1], z2=z[i+2], z3=z[i+3];
            if (z0 > tau){ s0 += z0; k0 += 1.f; }
            if (z1 > tau){ s1 += z1; k1 += 1.f; }
            if (z2 > tau){ s2 += z2; k2 += 1.f; }
            if (z3 > tau){ s3 += z3; k3 += 1.f; }
        }
        float ss = (s0+s1)+(s2+s3), kk = (k0+k1)+(k2+k3);
        #pragma unroll
        for (int off=1; off<16; off<<=1){
            ss += __shfl_xor(ss, off, 64);
            kk += __shfl_xor(kk, off, 64);
        }
        float tn = (ss - 1.0f) / kk;
        bool changed = (tn != tau);
        tau = tn;
        if (!__any(changed)) break;
    }

    // ---- Phase 3: p -> bf16 hi/lo into reused LDS (XOR-swizzled rows) -----
    ushort_t* Ph = (ushort_t*)sc;          // [16][512] bf16 hi, 16 KB
    ushort_t* Pl = Ph + 16*512;            // [16][512] bf16 lo, 16 KB
    {
        const int xr = (row & 7) << 3;     // ushort-index XOR (16B granular)
        #pragma unroll
        for (int g=0; g<8; g++){
            ushort4 vh4, vl4;
            ushort_t* hp = (ushort_t*)&vh4;
            ushort_t* lp = (ushort_t*)&vl4;
            #pragma unroll
            for (int u=0; u<4; u++){
                float p = z[g*4+u] - tau;
                p = p > 0.f ? p : 0.f;
                ushort_t hv = (ushort_t)(__float_as_uint(p) >> 16);  // trunc hi
                hp[u] = hv;
                lp[u] = f2bf(p - bf2f(hv));                          // RNE lo
            }
            int k = fr*32 + g*4;
            int idx = row*512 + (k ^ xr);
            *(ushort4*)&Ph[idx] = vh4;
            *(ushort4*)&Pl[idx] = vl4;
        }
    }
    __syncthreads();

    // ---- PV via MFMA: wave w computes d-slice [16w,16w+16) for all 16 rows
    const int d0 = wave * 16;
    const ushort_t* vph = Vthi + ((size_t)bh*DH_ + d0 + fr)*S_ + quad*8;
    const ushort_t* vpl = Vtlo + ((size_t)bh*DH_ + d0 + fr)*S_ + quad*8;
    const int xra = (fr & 7) << 3;
    const int abase = fr*512;

    f32x4 accv[2][3];
    #pragma unroll
    for (int a=0;a<2;a++)
        #pragma unroll
        for (int c=0;c<3;c++) accv[a][c] = (f32x4){0.f,0.f,0.f,0.f};

    #pragma unroll
    for (int c=0; c<16; c++){
        int kc = c*32;
        int aidx = abase + ((kc + quad*8) ^ xra);
        bf16x8 ah  = *(const bf16x8*)&Ph[aidx];
        bf16x8 al  = *(const bf16x8*)&Pl[aidx];
        bf16x8 bh8 = *(const bf16x8*)(vph + kc);
        bf16x8 bl8 = *(const bf16x8*)(vpl + kc);
        int par = c & 1;
        accv[par][0] = __builtin_amdgcn_mfma_f32_16x16x32_bf16(ah, bh8, accv[par][0], 0,0,0);
        accv[par][1] = __builtin_amdgcn_mfma_f32_16x16x32_bf16(al, bh8, accv[par][1], 0,0,0);
        accv[par][2] = __builtin_amdgcn_mfma_f32_16x16x32_bf16(ah, bl8, accv[par][2], 0,0,0);
    }
    f32x4 cs = ((accv[0][0]+accv[0][1]) + (accv[0][2]+accv[1][0]))
             +  (accv[1][1]+accv[1][2]);

    // C/D layout: col = lane&15 = d-offset, row = quad*4 + r = q-row
    size_t ob = ((size_t)(b*S_ + q0 + quad*4))*D_ + h*DH_ + d0 + fr;
    #pragma unroll
    for (int r=0; r<4; r++) out[ob + (size_t)r*D_] = cs[r];
}

// ---------------------------------------------------------------------------
extern "C" void kernel_launch(void* const* d_in, const int* in_sizes, int n_in,
                              void* d_out, int out_size, void* d_ws, size_t ws_size,
                              hipStream_t stream) {
    const float* hs   = (const float*)d_in[0];
    const float* mask = (const float*)d_in[1];
    const float* Wq   = (const float*)d_in[2];
    const float* bq   = (const float*)d_in[3];
    const float* Wk   = (const float*)d_in[4];
    const float* bk   = (const float*)d_in[5];
    const float* Wv   = (const float*)d_in[6];
    const float* bv   = (const float*)d_in[7];
    float* out = (float*)d_out;

    const size_t per = (size_t)BH_ * S_ * DH_;   // 6291456
    char* w = (char*)d_ws;
    ushort_t* vthi = (ushort_t*)w; w += per*2;
    ushort_t* vtlo = (ushort_t*)w; w += per*2;
    ushort_t* qhi  = (ushort_t*)w; w += per*2;
    ushort_t* qlo  = (ushort_t*)w; w += per*2;
    ushort_t* khi  = (ushort_t*)w; w += per*2;
    ushort_t* klo  = (ushort_t*)w; w += per*2;
    ushort_t* Xbf  = (ushort_t*)w; w += per*2;
    ushort_t* Whi  = (ushort_t*)w; w += (size_t)NTOT*D_*2;
    ushort_t* Wlo  = (ushort_t*)w;

    convert_x<<<(int)(per/4/256), 256, 0, stream>>>(hs, Xbf, (int)(per/4));
    convert_w<<<dim3(D_*D_/4/256, 1, 3), 256, 0, stream>>>(Wq, Wk, Wv, Whi, Wlo);

    dim3 ggrid(NTOT/BN, MTOT/BM);   // (18, 64)
    gemm_split<<<ggrid, 256, 0, stream>>>(Xbf, Whi, Wlo, bq, bk, bv,
                                          qhi, qlo, khi, klo, vthi, vtlo);

    attn_mfma<<<BH_*32, 256, 0, stream>>>(qhi, qlo, khi, klo, vthi, vtlo, mask, out);
}